// Round 4
// baseline (146.769 us; speedup 1.0000x reference)
//
#include <hip/hip_runtime.h>
#include <hip/hip_bf16.h>

// MechanismGrabber: B=2,S=4096,D=128,M=64. Outputs: integrated [8192,128] f32, vp [8192] f32.
// R4: single fused kernel (selector + mech-sum + integrate), 256 blocks = 128 tokTiles x 2 e-halves.
// selected = sum_m w[t,m]*(x@Wt[m]) + w@ (bt+char);  w = gate*score*timing;  victory via u_m = Wt[m]@Wv[m].
// integrate partial-summed across e-halves via f32 atomicAdd (out pre-zeroed by hipMemsetAsync).

typedef __bf16 bf16_t;
typedef __bf16 bf16x8 __attribute__((ext_vector_type(8)));
typedef float  f32x4  __attribute__((ext_vector_type(4)));

// ws layout (bytes)
#define WS_WTT      0u          // bf16 [m][ks(4)][e(128)][g(4)][j(8)]  (frag-major Wt^T), 2 MB
#define WS_W1T      2097152u    // bf16 [256 out][256 in]
#define WS_W2T      2228224u    // bf16 [64 out][256 in]
#define WS_OT       2260992u    // bf16 [64 out][64 in]
#define WS_WG       2269184u    // bf16 [64][128]
#define WS_U        2285568u    // bf16 [64][128]
#define WS_CVEC     2301952u    // f32  [64]
#define WS_BCT      2302208u    // bf16 [128 e][64 m]  (bt+char)^T
#define WS_WIT      2318592u    // bf16 [128 out][256 in]

#define VP_OFF 1048576

__device__ __forceinline__ f32x4 mfma16(bf16x8 a, bf16x8 b, f32x4 c) {
  return __builtin_amdgcn_mfma_f32_16x16x32_bf16(a, b, c, 0, 0, 0);
}

__device__ __forceinline__ float gelu_exact(float v) {
  return 0.5f * v * (1.0f + erff(v * 0.70710678118654752f));
}
__device__ __forceinline__ float sigmoidf_(float v) {
  return 1.0f / (1.0f + __expf(-v));
}

__device__ __forceinline__ bf16x8 cvt8(float4 v0, float4 v1) {
  bf16x8 a;
  a[0] = (bf16_t)v0.x; a[1] = (bf16_t)v0.y; a[2] = (bf16_t)v0.z; a[3] = (bf16_t)v0.w;
  a[4] = (bf16_t)v1.x; a[5] = (bf16_t)v1.y; a[6] = (bf16_t)v1.z; a[7] = (bf16_t)v1.w;
  return a;
}

// ---------------------------------------------------------------- kernel P (unchanged from R3)
__global__ __launch_bounds__(256) void kprep(
    const float* __restrict__ Wt, const float* __restrict__ bt,
    const float* __restrict__ ch, const float* __restrict__ Wg,
    const float* __restrict__ Wv, const float* __restrict__ bv,
    const float* __restrict__ O, const float* __restrict__ W1,
    const float* __restrict__ W2, const float* __restrict__ Wi,
    char* __restrict__ ws)
{
  const int bid = blockIdx.x, tid = threadIdx.x;
  if (bid < 128) {
    const int m = bid >> 1, half = bid & 1;
    const float* wtm = Wt + m * 16384;
    bf16_t* wtt = (bf16_t*)(ws + WS_WTT) + m * 16384;
    const int ks = half * 2 + (tid >> 7), e = tid & 127;
    bf16_t tmp[32];
    #pragma unroll
    for (int dd = 0; dd < 32; ++dd)
      tmp[dd] = (bf16_t)wtm[(ks * 32 + dd) * 128 + e];
    bf16_t* dst = wtt + ks * 4096 + e * 32;
    #pragma unroll
    for (int g = 0; g < 4; ++g)
      *(bf16x8*)(dst + g * 8) = *(const bf16x8*)(tmp + g * 8);
    if (half == 0) {
      if (tid < 128) {
        const float* wvm = Wv + m * 128;
        float s = 0.f;
        for (int e2 = 0; e2 < 128; ++e2) s += wtm[tid * 128 + e2] * wvm[e2];
        ((bf16_t*)(ws + WS_U))[m * 128 + tid] = (bf16_t)s;
      } else if (tid == 128) {
        const float* wvm = Wv + m * 128;
        float s = bv[m];
        for (int e2 = 0; e2 < 128; ++e2) s += (bt[m * 128 + e2] + ch[m * 128 + e2]) * wvm[e2];
        ((float*)(ws + WS_CVEC))[m] = s;
      }
    }
  } else if (bid < 144) {
    int base = (bid - 128) * 256 + tid;
    int k = base >> 4, c0 = (base & 15) * 16;
    bf16_t* o = (bf16_t*)(ws + WS_W1T);
    #pragma unroll
    for (int j = 0; j < 16; ++j) o[(c0 + j) * 256 + k] = (bf16_t)W1[k * 256 + c0 + j];
  } else if (bid < 146) {
    int base = (bid - 144) * 256 + tid;
    int k = base >> 1, c0 = (base & 1) * 32;
    bf16_t* o = (bf16_t*)(ws + WS_W2T);
    #pragma unroll
    for (int j = 0; j < 32; ++j) o[(c0 + j) * 256 + k] = (bf16_t)W2[k * 64 + c0 + j];
  } else if (bid == 146) {
    int k = tid >> 2, c0 = (tid & 3) * 16;
    bf16_t* o = (bf16_t*)(ws + WS_OT);
    #pragma unroll
    for (int j = 0; j < 16; ++j) o[(c0 + j) * 64 + k] = (bf16_t)O[k * 64 + c0 + j];
  } else if (bid == 147) {
    bf16_t* o = (bf16_t*)(ws + WS_WG);
    #pragma unroll
    for (int j = 0; j < 32; ++j) o[tid * 32 + j] = (bf16_t)Wg[tid * 32 + j];
  } else if (bid == 148) {
    bf16_t* o = (bf16_t*)(ws + WS_BCT);
    #pragma unroll
    for (int i = 0; i < 4; ++i) {
      int task = tid + i * 256;
      int m = task >> 4, e0 = (task & 15) * 8;
      #pragma unroll
      for (int j = 0; j < 8; ++j)
        o[(e0 + j) * 64 + m] = (bf16_t)(bt[m * 128 + e0 + j] + ch[m * 128 + e0 + j]);
    }
  } else {
    int base = (bid - 149) * 256 + tid;
    int k = base >> 2, c0 = (base & 3) * 32;
    bf16_t* o = (bf16_t*)(ws + WS_WIT);
    #pragma unroll
    for (int j = 0; j < 32; ++j) o[(c0 + j) * 256 + k] = (bf16_t)Wi[k * 128 + c0 + j];
  }
}

// ---------------------------------------------------------------- fused kernel
__device__ __forceinline__ void loadF(bf16x8 (&F)[4], const char* bbase, int m) {
  const char* p = bbase + m * 32768;
  F[0] = *(const bf16x8*)(p);
  F[1] = *(const bf16x8*)(p + 8192);
  F[2] = *(const bf16x8*)(p + 16384);
  F[3] = *(const bf16x8*)(p + 24576);
}

template<int J>
__device__ __forceinline__ void computeT(const bf16x8 (&F)[4], const f32x4 (&wc)[16],
                                         const bf16x8 (&aSel)[4][8], f32x4 (&acc)[4]) {
  #pragma unroll
  for (int rg = 0; rg < 4; ++rg) {
    f32x4 y = {0.f, 0.f, 0.f, 0.f};
    #pragma unroll
    for (int ks = 0; ks < 4; ++ks) y = mfma16(aSel[rg][ks], F[ks], y);
    #pragma unroll
    for (int jj = 0; jj < 4; ++jj)
      acc[rg][jj] += wc[rg * 4 + jj][J] * y[jj];
  }
}

__global__ __launch_bounds__(256, 1) void kfused(
    const float* __restrict__ x, const float* __restrict__ ctx,
    const float* __restrict__ b1, const float* __restrict__ b2,
    const float* __restrict__ bg, const float* __restrict__ bi,
    char* __restrict__ ws, float* __restrict__ out)
{
  __shared__ char sm[92160];
  bf16_t* hL      = (bf16_t*)sm;               // [64][256] bf16 swz, 32 KB
  float*  scoresL = (float*)(sm + 32768);      // [64][64]  f32 (logits then scores), 16 KB
  float*  wL      = (float*)(sm + 49152);      // [64][68]  f32 padded, 17.4 KB
  bf16_t* scbL    = (bf16_t*)(sm + 66560);     // [64][64]  bf16 swz, 8 KB
  bf16_t* wbL     = (bf16_t*)(sm + 74752);     // [64][64]  bf16 swz, 8 KB
  bf16_t* selL    = (bf16_t*)(sm + 82944);     // [64][64]  bf16 swz, 8 KB
  float*  vpL     = (float*)(sm + 91136);      // [64][4]

  const int tid = threadIdx.x;
  const int lane = tid & 63, wid = tid >> 6;
  const int tb = (blockIdx.x >> 1) * 64;
  const int eh = blockIdx.x & 1;
  const int lr = lane & 15;
  const int lg = lane >> 4;
  const int lk = lg * 8;
  const int lj4 = lg * 4;

  const bf16_t* W1t = (const bf16_t*)(ws + WS_W1T);
  const bf16_t* W2t = (const bf16_t*)(ws + WS_W2T);
  const bf16_t* Ot  = (const bf16_t*)(ws + WS_OT);
  const bf16_t* Wgb = (const bf16_t*)(ws + WS_WG);
  const bf16_t* Ub  = (const bf16_t*)(ws + WS_U);
  const float*  cv  = (const float*)(ws + WS_CVEC);
  const bf16_t* bct = (const bf16_t*)(ws + WS_BCT);
  const bf16_t* Wit = (const bf16_t*)(ws + WS_WIT);
  const char*  wttc = (const char*)(ws + WS_WTT);

  // ---------------- phase A: selector (all 64 tokens; duplicated across eh pair)
  bf16x8 aSel[4][8];  // [rg][ks]: rows tb+rg*16+lr, k=ks*32+lk ; ks<4 = x, ks>=4 = ctx
  #pragma unroll
  for (int rg = 0; rg < 4; ++rg) {
    int t = tb + rg * 16 + lr;
    #pragma unroll
    for (int ks = 0; ks < 8; ++ks) {
      const float* src = (ks < 4) ? (x + t * 128 + ks * 32 + lk)
                                  : (ctx + t * 128 + (ks - 4) * 32 + lk);
      aSel[rg][ks] = cvt8(*(const float4*)src, *(const float4*)(src + 4));
    }
  }

  // GEMM1: [64,256]@W1 -> gelu -> hL (each wave owns 64 hidden cols)
  #pragma unroll
  for (int cg = 0; cg < 4; ++cg) {
    int c = wid * 64 + cg * 16 + lr;
    f32x4 a[4] = {{0,0,0,0},{0,0,0,0},{0,0,0,0},{0,0,0,0}};
    #pragma unroll
    for (int ks = 0; ks < 8; ++ks) {
      bf16x8 b = *(const bf16x8*)(W1t + c * 256 + ks * 32 + lk);
      #pragma unroll
      for (int rg = 0; rg < 4; ++rg) a[rg] = mfma16(aSel[rg][ks], b, a[rg]);
    }
    float bb = b1[c];
    #pragma unroll
    for (int rg = 0; rg < 4; ++rg)
      #pragma unroll
      for (int j = 0; j < 4; ++j) {
        int r = rg * 16 + lj4 + j;
        float v = gelu_exact(a[rg][j] + bb);
        *(bf16_t*)((char*)hL + ((r * 512 + c * 2) ^ ((r & 7) << 4))) = (bf16_t)v;
      }
  }
  __syncthreads();

  // GEMM2: h@W2 + b2 -> logits (each wave owns 16 mech cols)
  {
    int c = wid * 16 + lr;
    f32x4 l[4] = {{0,0,0,0},{0,0,0,0},{0,0,0,0},{0,0,0,0}};
    #pragma unroll
    for (int ks = 0; ks < 8; ++ks) {
      int k0 = ks * 32 + lk;
      bf16x8 b = *(const bf16x8*)(W2t + c * 256 + k0);
      #pragma unroll
      for (int rg = 0; rg < 4; ++rg) {
        int r = rg * 16 + lr;
        bf16x8 a = *(const bf16x8*)((char*)hL + ((r * 512 + k0 * 2) ^ ((r & 7) << 4)));
        l[rg] = mfma16(a, b, l[rg]);
      }
    }
    float bb = b2[c];
    #pragma unroll
    for (int rg = 0; rg < 4; ++rg)
      #pragma unroll
      for (int j = 0; j < 4; ++j)
        scoresL[(rg * 16 + lj4 + j) * 64 + c] = l[rg][j] + bb;
  }
  __syncthreads();

  // softmax over 64 mechs (4 threads/row x 16 each)
  {
    int row = tid >> 2, i = tid & 3;
    float v[16];
    #pragma unroll
    for (int j = 0; j < 16; ++j) v[j] = scoresL[row * 64 + i * 16 + j];
    float mx = v[0];
    #pragma unroll
    for (int j = 1; j < 16; ++j) mx = fmaxf(mx, v[j]);
    mx = fmaxf(mx, __shfl_xor(mx, 1));
    mx = fmaxf(mx, __shfl_xor(mx, 2));
    float sum = 0.f;
    #pragma unroll
    for (int j = 0; j < 16; ++j) { v[j] = __expf(v[j] - mx); sum += v[j]; }
    sum += __shfl_xor(sum, 1);
    sum += __shfl_xor(sum, 2);
    float inv = 1.0f / sum;
    #pragma unroll
    for (int j = 0; j < 16; ++j) {
      float s = v[j] * inv;
      int cc = i * 16 + j;
      scoresL[row * 64 + cc] = s;
      *(bf16_t*)((char*)scbL + ((row * 128 + cc * 2) ^ ((row & 7) << 4))) = (bf16_t)s;
    }
  }
  __syncthreads();

  // gates / timing / victory / w  (each wave owns 16 mech cols)
  {
    const int c = wid * 16 + lr;
    f32x4 g[4] = {{0,0,0,0},{0,0,0,0},{0,0,0,0},{0,0,0,0}};
    #pragma unroll
    for (int ks = 0; ks < 2; ++ks) {
      int k0 = ks * 32 + lk;
      bf16x8 b = *(const bf16x8*)(Ot + c * 64 + k0);
      #pragma unroll
      for (int rg = 0; rg < 4; ++rg) {
        int r = rg * 16 + lr;
        bf16x8 a = *(const bf16x8*)((char*)scbL + ((r * 128 + k0 * 2) ^ ((r & 7) << 4)));
        g[rg] = mfma16(a, b, g[rg]);
      }
    }
    f32x4 t[4] = {{0,0,0,0},{0,0,0,0},{0,0,0,0},{0,0,0,0}};
    f32x4 v[4] = {{0,0,0,0},{0,0,0,0},{0,0,0,0},{0,0,0,0}};
    #pragma unroll
    for (int ks = 0; ks < 4; ++ks) {
      bf16x8 bT = *(const bf16x8*)(Wgb + c * 128 + ks * 32 + lk);
      bf16x8 bV = *(const bf16x8*)(Ub  + c * 128 + ks * 32 + lk);
      #pragma unroll
      for (int rg = 0; rg < 4; ++rg) {
        t[rg] = mfma16(aSel[rg][ks], bT, t[rg]);
        v[rg] = mfma16(aSel[rg][ks], bV, v[rg]);
      }
    }
    float bgc = bg[c], cvc = cv[c];
    #pragma unroll
    for (int rg = 0; rg < 4; ++rg)
      #pragma unroll
      for (int j = 0; j < 4; ++j) {
        int r = rg * 16 + lj4 + j;
        float gate = 1.0f + tanhf(g[rg][j]);
        float tim  = sigmoidf_(t[rg][j] + bgc);
        float vic  = sigmoidf_(v[rg][j] + cvc);
        float sc   = scoresL[r * 64 + c];
        float w    = gate * sc * tim;
        wL[r * 68 + c] = w;
        *(bf16_t*)((char*)wbL + ((r * 128 + c * 2) ^ ((r & 7) << 4))) = (bf16_t)w;
        float pv = vic * sc;
        pv += __shfl_xor(pv, 1); pv += __shfl_xor(pv, 2);
        pv += __shfl_xor(pv, 4); pv += __shfl_xor(pv, 8);
        if (lr == 0) vpL[r * 4 + wid] = pv;
      }
  }
  __syncthreads();

  // vp finalize (eh==0 only)
  if (eh == 0 && tid < 64) {
    float s = vpL[tid * 4 + 0] + vpL[tid * 4 + 1] + vpL[tid * 4 + 2] + vpL[tid * 4 + 3];
    out[VP_OFF + tb + tid] = s;
  }

  // sbias = w @ (bt+char)_half -> directly into phase-B accumulators.
  const int wcol = wid * 16;
  f32x4 acc[4] = {{0,0,0,0},{0,0,0,0},{0,0,0,0},{0,0,0,0}};
  {
    int eg = eh * 64 + wcol + lr;
    #pragma unroll
    for (int ks = 0; ks < 2; ++ks) {
      int k0 = ks * 32 + lk;
      bf16x8 b = *(const bf16x8*)(bct + eg * 64 + k0);
      #pragma unroll
      for (int rg = 0; rg < 4; ++rg) {
        int r = rg * 16 + lr;
        bf16x8 a = *(const bf16x8*)((char*)wbL + ((r * 128 + k0 * 2) ^ ((r & 7) << 4)));
        acc[rg] = mfma16(a, b, acc[rg]);
      }
    }
  }

  // ---------------- phase B: acc += sum_m w[:,m] * (x @ Wt[m])[:, half]  (barrier-free)
  const char* bbase = wttc + (size_t)(((eh * 64 + wcol + lr) * 32 + lg * 8) * 2);
  bf16x8 F0[4], F1[4], F2[4], F3[4];
  loadF(F0, bbase, 0);
  loadF(F1, bbase, 1);
  loadF(F2, bbase, 2);

  for (int it = 0; it < 16; ++it) {
    const int base = it * 4;
    f32x4 wc[16];
    #pragma unroll
    for (int rg = 0; rg < 4; ++rg)
      #pragma unroll
      for (int jj = 0; jj < 4; ++jj)
        wc[rg * 4 + jj] = *(const f32x4*)(&wL[(rg * 16 + lj4 + jj) * 68 + base]);
    int n4 = base + 4 > 63 ? 63 : base + 4;
    int n5 = base + 5 > 63 ? 63 : base + 5;
    int n6 = base + 6 > 63 ? 63 : base + 6;
    loadF(F3, bbase, base + 3);
    computeT<0>(F0, wc, aSel, acc);
    loadF(F0, bbase, n4);
    computeT<1>(F1, wc, aSel, acc);
    loadF(F1, bbase, n5);
    computeT<2>(F2, wc, aSel, acc);
    loadF(F2, bbase, n6);
    computeT<3>(F3, wc, aSel, acc);
  }

  // ---------------- phase C: integrate partial = [x | sel_half] @ Wi_rows (+ bi on eh==0)
  #pragma unroll
  for (int rg = 0; rg < 4; ++rg)
    #pragma unroll
    for (int j = 0; j < 4; ++j) {
      int r = rg * 16 + lj4 + j;
      int cl = wcol + lr;
      *(bf16_t*)((char*)selL + ((r * 128 + cl * 2) ^ ((r & 7) << 4))) = (bf16_t)acc[rg][j];
    }
  __syncthreads();

  #pragma unroll
  for (int cg = 0; cg < 2; ++cg) {
    int c = wid * 32 + cg * 16 + lr;
    f32x4 a[4] = {{0,0,0,0},{0,0,0,0},{0,0,0,0},{0,0,0,0}};
    #pragma unroll
    for (int ks = 0; ks < 2; ++ks) {
      int k0 = ks * 32 + lk;
      bf16x8 b = *(const bf16x8*)(Wit + c * 256 + 128 + eh * 64 + k0);
      #pragma unroll
      for (int rg = 0; rg < 4; ++rg) {
        int r = rg * 16 + lr;
        bf16x8 av = *(const bf16x8*)((char*)selL + ((r * 128 + k0 * 2) ^ ((r & 7) << 4)));
        a[rg] = mfma16(av, b, a[rg]);
      }
    }
    if (eh == 0) {
      #pragma unroll
      for (int ks = 0; ks < 4; ++ks) {
        bf16x8 b = *(const bf16x8*)(Wit + c * 256 + ks * 32 + lk);
        #pragma unroll
        for (int rg = 0; rg < 4; ++rg) a[rg] = mfma16(aSel[rg][ks], b, a[rg]);
      }
    }
    float bb = (eh == 0) ? bi[c] : 0.0f;
    #pragma unroll
    for (int rg = 0; rg < 4; ++rg)
      #pragma unroll
      for (int j = 0; j < 4; ++j)
        atomicAdd(&out[(tb + rg * 16 + lj4 + j) * 128 + c], a[rg][j] + bb);
  }
}

// ---------------------------------------------------------------- launch
extern "C" void kernel_launch(void* const* d_in, const int* in_sizes, int n_in,
                              void* d_out, int out_size, void* d_ws, size_t ws_size,
                              hipStream_t stream)
{
  (void)in_sizes; (void)n_in; (void)ws_size;
  const float* x   = (const float*)d_in[0];
  const float* ctx = (const float*)d_in[1];
  const float* Wt  = (const float*)d_in[2];
  const float* bt  = (const float*)d_in[3];
  const float* ch  = (const float*)d_in[4];
  const float* Wg  = (const float*)d_in[5];
  const float* bg  = (const float*)d_in[6];
  const float* Wv  = (const float*)d_in[7];
  const float* bv  = (const float*)d_in[8];
  const float* O   = (const float*)d_in[9];
  const float* W1  = (const float*)d_in[10];
  const float* b1  = (const float*)d_in[11];
  const float* W2  = (const float*)d_in[12];
  const float* b2  = (const float*)d_in[13];
  const float* Wi  = (const float*)d_in[14];
  const float* bi  = (const float*)d_in[15];
  float* out = (float*)d_out;
  char* ws = (char*)d_ws;

  hipMemsetAsync(d_out, 0, (size_t)out_size * 4, stream);
  kprep<<<153, 256, 0, stream>>>(Wt, bt, ch, Wg, Wv, bv, O, W1, W2, Wi, ws);
  kfused<<<256, 256, 0, stream>>>(x, ctx, b1, b2, bg, bi, ws, out);
}